// Round 1
// baseline (119.245 us; speedup 1.0000x reference)
//
#include <hip/hip_runtime.h>
#include <math.h>

#define K_TOP   8
#define EPS_F   1e-8f
#define T_DIM   2048
#define H_DIM   1024
#define NHEADS  16

__global__ __launch_bounds__(256, 1) void ctma_topk_agg_kernel(
    const float* __restrict__ mlp,   // [B, T, H]
    const float* __restrict__ attn,  // [B, Hh, T, T]
    float* __restrict__ out)         // [B, T, H]
{
    const int tid = threadIdx.x;
    const int row = blockIdx.x;      // b*T + t
    const int b   = row >> 11;       // / 2048
    const int t   = row & (T_DIM - 1);

    __shared__ float s_row[T_DIM];   // head-mean attention row
    __shared__ float s_rv[4];        // per-wave reduce partials (val)
    __shared__ int   s_ri[4];        // per-wave reduce partials (idx)
    __shared__ float s_vals[K_TOP];
    __shared__ int   s_idx[K_TOP];

    // ---------------- Phase 1: head-mean row -> LDS ----------------
    // attn row base for (b, head=0, t): offset b*Hh*T*T + t*T floats
    const float4* attn4 = reinterpret_cast<const float4*>(
        attn + (size_t)b * NHEADS * T_DIM * T_DIM + (size_t)t * T_DIM);
    const size_t head_stride4 = (size_t)T_DIM * T_DIM / 4;

    float acc[8];
    #pragma unroll
    for (int j = 0; j < 8; ++j) acc[j] = 0.0f;

    #pragma unroll 4
    for (int h = 0; h < NHEADS; ++h) {
        float4 a = attn4[(size_t)h * head_stride4 + tid];
        float4 c = attn4[(size_t)h * head_stride4 + 256 + tid];
        acc[0] += a.x; acc[1] += a.y; acc[2] += a.z; acc[3] += a.w;
        acc[4] += c.x; acc[5] += c.y; acc[6] += c.z; acc[7] += c.w;
    }

    const float inv16 = 1.0f / (float)NHEADS;
    #pragma unroll
    for (int j = 0; j < 4; ++j) s_row[4 * tid + j]        = acc[j]     * inv16;
    #pragma unroll
    for (int j = 0; j < 4; ++j) s_row[1024 + 4 * tid + j] = acc[4 + j] * inv16;
    __syncthreads();

    // ---------------- Phase 2: iterative top-8 ----------------
    // Argmax with LOWEST-index tie-break (matches jax.lax.top_k stability).
    const int lane = tid & 63;
    const int wave = tid >> 6;

    for (int k = 0; k < K_TOP; ++k) {
        float best = -INFINITY;
        int   bidx = 0x7fffffff;
        // each thread scans 8 elements at stride 256 (indices ascending)
        #pragma unroll
        for (int j = 0; j < 8; ++j) {
            const int i = tid + j * 256;
            const float v = s_row[i];
            if (v > best) { best = v; bidx = i; }
            // equal case: scan order has ascending i, so first (lower) kept
        }
        // wave-level reduce (64 lanes)
        #pragma unroll
        for (int off = 32; off > 0; off >>= 1) {
            const float ov = __shfl_down(best, off);
            const int   oi = __shfl_down(bidx, off);
            if (ov > best || (ov == best && oi < bidx)) { best = ov; bidx = oi; }
        }
        if (lane == 0) { s_rv[wave] = best; s_ri[wave] = bidx; }
        __syncthreads();
        if (tid == 0) {
            float bv = s_rv[0]; int bi = s_ri[0];
            #pragma unroll
            for (int w = 1; w < 4; ++w) {
                const float ov = s_rv[w]; const int oi = s_ri[w];
                if (ov > bv || (ov == bv && oi < bi)) { bv = ov; bi = oi; }
            }
            s_vals[k] = bv;
            s_idx[k]  = bi;
            s_row[bi] = -INFINITY;   // remove for next round
        }
        __syncthreads();
    }

    // ---------------- Phase 3: renormalize + gather-weighted sum ----------------
    float wsum = 0.0f;
    #pragma unroll
    for (int k = 0; k < K_TOP; ++k) wsum += s_vals[k];
    wsum = fmaxf(wsum, EPS_F);
    const float invs = 1.0f / wsum;

    const float4* mlp4 = reinterpret_cast<const float4*>(mlp)
                       + (size_t)b * T_DIM * (H_DIM / 4);
    float4 o = make_float4(0.f, 0.f, 0.f, 0.f);
    #pragma unroll
    for (int k = 0; k < K_TOP; ++k) {
        const float w = s_vals[k] * invs;
        const float4 m = mlp4[(size_t)s_idx[k] * (H_DIM / 4) + tid];
        o.x += w * m.x; o.y += w * m.y; o.z += w * m.z; o.w += w * m.w;
    }
    reinterpret_cast<float4*>(out)[(size_t)row * (H_DIM / 4) + tid] = o;
}

extern "C" void kernel_launch(void* const* d_in, const int* in_sizes, int n_in,
                              void* d_out, int out_size, void* d_ws, size_t ws_size,
                              hipStream_t stream) {
    const float* mlp  = (const float*)d_in[0];   // [B, T, H] fp32
    const float* attn = (const float*)d_in[1];   // [B, Hh, T, T] fp32
    float* out = (float*)d_out;                  // [B, T, H] fp32

    const int B = in_sizes[0] / (T_DIM * H_DIM); // = 2
    const int nblocks = B * T_DIM;               // 4096 rows

    ctma_topk_agg_kernel<<<nblocks, 256, 0, stream>>>(mlp, attn, out);
}